// Round 1
// baseline (492.681 us; speedup 1.0000x reference)
//
#include <hip/hip_runtime.h>
#include <cstdint>

// ---------------------------------------------------------------------------
// SelfAttention (QK-l2norm variant), MI355X/gfx950.
// Pipeline: split(x,w,p) -> biasscan -> splitGEMM1(qkv, scatter to [3,B,H,L,D] bf16)
//           -> l2norm(q,k)+scale -> flash-attn bf16 (out as hi/lo bf16 split)
//           -> splitGEMM2 -> d_out f32
// Precision: projections use Markidis hi/lo bf16 split (3 MFMAs) ~ fp32-accurate;
// attention plain bf16 post-normalization (error budget ~1e-4 std).
// ---------------------------------------------------------------------------

typedef __bf16 bfx8 __attribute__((ext_vector_type(8)));
typedef __bf16 bfx4 __attribute__((ext_vector_type(4)));
typedef float  f32x4 __attribute__((ext_vector_type(4)));

#define NB   4
#define NH   16
#define SEQ  2048
#define CH   1024
#define DD   64
#define MROWS (NB*SEQ)             /* 8192 */
#define BHLD  (NB*NH*SEQ*DD)       /* 8388608 */

__device__ __forceinline__ void async16(void* lds, const void* g) {
  __builtin_amdgcn_global_load_lds((const __attribute__((address_space(1))) void*)g,
                                   (__attribute__((address_space(3))) void*)lds, 16, 0, 0);
}
__device__ __forceinline__ f32x4 mfma16(bfx8 a, bfx8 b, f32x4 c) {
  return __builtin_amdgcn_mfma_f32_16x16x32_bf16(a, b, c, 0, 0, 0);
}

// --------------------------- hi/lo split (Markidis) -------------------------
__global__ __launch_bounds__(256) void split_kernel(const float4* __restrict__ src,
                                                    __bf16* __restrict__ hi,
                                                    __bf16* __restrict__ lo, int n4) {
  int i = blockIdx.x * 256 + threadIdx.x;
  if (i >= n4) return;
  float4 v = src[i];
  float vv[4] = {v.x, v.y, v.z, v.w};
  bfx4 h, l;
  #pragma unroll
  for (int j = 0; j < 4; ++j) {
    __bf16 hb = (__bf16)vv[j];
    h[j] = hb;
    l[j] = (__bf16)(vv[j] - (float)hb);   // exact residual (Sterbenz), then RNE
  }
  *(bfx4*)(hi + 4*(size_t)i) = h;
  *(bfx4*)(lo + 4*(size_t)i) = l;
}

// --------------------------- bias nonzero scan ------------------------------
__global__ __launch_bounds__(256) void scan_nz(const uint4* __restrict__ p, int n4,
                                               int* __restrict__ flag) {
  unsigned acc = 0;
  const int stride = gridDim.x * 256;
  for (int i = blockIdx.x * 256 + threadIdx.x; i < n4; i += stride) {
    uint4 u = p[i];
    acc |= (u.x | u.y | u.z | u.w) & 0x7fffffffu;  // ignore sign bits (-0.0 == no bias)
  }
  if (acc) atomicOr(flag, 1);
}

// --------------------------- split-bf16 GEMM (NT) ---------------------------
// C[M,N] = A[M,K] * B[N,K]^T, A/B given as hi/lo bf16 pairs (K-contiguous).
// 128x128 tile, 4 waves (2x2 of 64x64), BK=32, mfma_f32_16x16x32_bf16.
// LDS tiles [128][32] bf16, 4 chunks/row of 16B, swizzle chunk ^= (row>>1)&3.
// EPI==1: +concat(q_bias,0,v_bias), scatter bf16 -> qkvn[3][B,H,L,D]
// EPI==2: +proj_b, write f32 d_out
template<int EPI>
__global__ __launch_bounds__(256, 2) void gemm128(
    const __bf16* __restrict__ Agh, const __bf16* __restrict__ Agl,
    const __bf16* __restrict__ Bgh, const __bf16* __restrict__ Bgl,
    const int Ntiles, const int K,
    const float* __restrict__ biasA, const float* __restrict__ biasB,
    float* __restrict__ outF, __bf16* __restrict__ outQ)
{
  __shared__ alignas(16) char lds[32768];   // Ah | Al | Bh | Bl, 8KB each
  const int tid = threadIdx.x;
  const int lane = tid & 63, w = tid >> 6;
  const int l15 = lane & 15, l4 = lane >> 4;
  const int nwg = (int)gridDim.x;
  const int wk = (int)(blockIdx.x & 7) * (nwg >> 3) + (int)(blockIdx.x >> 3); // XCD swizzle (nwg%8==0)
  const int mt = wk / Ntiles, nt = wk % Ntiles;
  const int m0 = mt * 128, n0 = nt * 128;
  const int wm = (w >> 1) * 64, wn = (w & 1) * 64;

  const f32x4 zz = {0.f, 0.f, 0.f, 0.f};
  f32x4 acc[4][4];
  #pragma unroll
  for (int a = 0; a < 4; ++a)
    #pragma unroll
    for (int b = 0; b < 4; ++b) acc[a][b] = zz;

  // staging geometry: slot s = i*256+tid -> LDS byte s*16; row=s>>2, pos=s&3,
  // logical k-chunk c = pos ^ ((row>>1)&3)  (involution; read side matches)
  int st_row[2], st_c[2], st_lds[2];
  #pragma unroll
  for (int i = 0; i < 2; ++i) {
    const int s = i*256 + tid;
    st_row[i] = s >> 2;
    st_c[i]   = (s & 3) ^ ((st_row[i] >> 1) & 3);
    st_lds[i] = (i*256 + w*64) * 16;     // wave-uniform base; HW adds lane*16
  }

  for (int k0 = 0; k0 < K; k0 += 32) {
    __syncthreads();
    #pragma unroll
    for (int i = 0; i < 2; ++i) {
      const size_t ga = (size_t)(m0 + st_row[i]) * K + (size_t)(k0 + st_c[i]*8);
      const size_t gb = (size_t)(n0 + st_row[i]) * K + (size_t)(k0 + st_c[i]*8);
      async16(lds +         st_lds[i], Agh + ga);
      async16(lds +  8192 + st_lds[i], Agl + ga);
      async16(lds + 16384 + st_lds[i], Bgh + gb);
      async16(lds + 24576 + st_lds[i], Bgl + gb);
    }
    __syncthreads();

    bfx8 ah[4], al[4], bh[4], bl[4];
    #pragma unroll
    for (int f = 0; f < 4; ++f) {
      const int ra = wm + f*16 + l15;
      const int oa = ra*64 + ((l4 ^ ((ra >> 1) & 3)) * 16);
      ah[f] = *(const bfx8*)(lds + oa);
      al[f] = *(const bfx8*)(lds + 8192 + oa);
      const int rb = wn + f*16 + l15;
      const int ob = rb*64 + ((l4 ^ ((rb >> 1) & 3)) * 16);
      bh[f] = *(const bfx8*)(lds + 16384 + ob);
      bl[f] = *(const bfx8*)(lds + 24576 + ob);
    }
    #pragma unroll
    for (int mf = 0; mf < 4; ++mf)
      #pragma unroll
      for (int nf = 0; nf < 4; ++nf) {
        acc[mf][nf] = mfma16(al[mf], bh[nf], acc[mf][nf]);
        acc[mf][nf] = mfma16(ah[mf], bl[nf], acc[mf][nf]);
        acc[mf][nf] = mfma16(ah[mf], bh[nf], acc[mf][nf]);
      }
  }

  // epilogue: C/D layout col=lane&15, row=4*(lane>>4)+reg  [m89/m91 verified]
  #pragma unroll
  for (int mf = 0; mf < 4; ++mf)
    #pragma unroll
    for (int nf = 0; nf < 4; ++nf)
      #pragma unroll
      for (int rg = 0; rg < 4; ++rg) {
        const int gr = m0 + wm + mf*16 + 4*l4 + rg;
        const int gc = n0 + wn + nf*16 + l15;
        float v = acc[mf][nf][rg];
        if (EPI == 1) {
          v += (gc < CH) ? biasA[gc] : ((gc >= 2*CH) ? biasB[gc - 2*CH] : 0.f);
          const int which = gc >> 10, cc = gc & (CH-1);
          const int hh = cc >> 6, dd = cc & 63;
          const int bb = gr >> 11, ll = gr & (SEQ-1);
          outQ[(size_t)which*BHLD + ((size_t)((bb*NH + hh)*SEQ) + ll)*DD + dd] = (__bf16)v;
        } else {
          outF[(size_t)gr*CH + gc] = v + biasA[gc];
        }
      }
}

// --------------------------- l2 normalize q,k (in place) --------------------
// rows 0..131071 = q (scaled by exp(min(scale_mul,log100))), 131072.. = k
__global__ __launch_bounds__(256) void norml2(__bf16* __restrict__ qk,
                                              const float* __restrict__ scale_mul) {
  const int tid = threadIdx.x;
  const int rid = blockIdx.x * 32 + (tid >> 3);
  const int e0 = (tid & 7) * 8;
  const int r = rid & (131072 - 1);
  const bool isq = rid < 131072;
  const int hh = (r >> 11) & 15;
  float sm = 1.f;
  if (isq) sm = __expf(fminf(scale_mul[hh], 4.605170185988091f)); // log(100)
  __bf16* p = qk + (size_t)rid * DD + e0;
  bfx8 v = *(bfx8*)p;
  float f[8]; float ss = 0.f;
  #pragma unroll
  for (int j = 0; j < 8; ++j) { f[j] = (float)v[j]; ss += f[j]*f[j]; }
  ss += __shfl_xor(ss, 1); ss += __shfl_xor(ss, 2); ss += __shfl_xor(ss, 4);
  const float sc = sm / fmaxf(sqrtf(ss), 1e-12f);
  #pragma unroll
  for (int j = 0; j < 8; ++j) v[j] = (__bf16)(f[j] * sc);
  *(bfx8*)p = v;
}

// --------------------------- flash attention (bf16) -------------------------
// One block = (b,h,qtile of 128). 4 waves x 32 q-rows. KV tiles of 128.
// K staged via global_load_lds (src pre-swizzled, chunk ^= row&7, 8x16B/row).
// V staged regs->LDS transposed Vt[64][128] (chunk ^= d&15, 16x16B/row).
// P routed via per-wave LDS (chunk ^= row&15) to reach A-operand layout.
__global__ __launch_bounds__(256, 2) void attn_kernel(
    const __bf16* __restrict__ qn, const __bf16* __restrict__ kn,
    const __bf16* __restrict__ vn,
    const float* __restrict__ bias, const int* __restrict__ flag,
    __bf16* __restrict__ ao_hi, __bf16* __restrict__ ao_lo)
{
  __shared__ alignas(16) char Ks[16384];
  __shared__ alignas(16) char Vt[16384];
  __shared__ alignas(16) char Ps[4][8192];

  const int tid = threadIdx.x, lane = tid & 63, w = tid >> 6;
  const int l15 = lane & 15, l4 = lane >> 4;
  const int wk = (int)(blockIdx.x & 7) * 128 + (int)(blockIdx.x >> 3); // XCD swizzle
  const int qt = wk & 15, h = (wk >> 4) & 15, b = wk >> 8;
  const size_t bh = ((size_t)(b*NH + h)) * SEQ * DD;
  const int hasbias = *flag;

  // Q fragments resident: A-operand row=lane&15, k = 8*(lane>>4)+j (contiguous)
  bfx8 Qf[2][2];
  const int q0 = qt*128 + w*32;
  #pragma unroll
  for (int mf = 0; mf < 2; ++mf)
    #pragma unroll
    for (int kd = 0; kd < 2; ++kd)
      Qf[mf][kd] = *(const bfx8*)(qn + bh + (size_t)(q0 + mf*16 + l15)*DD + kd*32 + l4*8);

  const f32x4 zz = {0.f, 0.f, 0.f, 0.f};
  f32x4 O[2][4];
  float m_[2][4], l_[2][4];
  #pragma unroll
  for (int mf = 0; mf < 2; ++mf) {
    #pragma unroll
    for (int rg = 0; rg < 4; ++rg) { m_[mf][rg] = -1e30f; l_[mf][rg] = 0.f; }
    #pragma unroll
    for (int nd = 0; nd < 4; ++nd) O[mf][nd] = zz;
  }

  for (int t = 0; t < 16; ++t) {
    __syncthreads();   // everyone done reading Ks/Vt from previous tile

    // ---- stage K tile (async, swizzled source) ----
    const __bf16* ksrc = kn + bh + (size_t)t*128*DD;
    #pragma unroll
    for (int i = 0; i < 4; ++i) {
      const int s = i*256 + tid;
      const int row = s >> 3;
      const int c = (s & 7) ^ (row & 7);
      async16(Ks + (size_t)(i*256 + w*64)*16, ksrc + (size_t)row*DD + c*8);
    }
    // ---- stage V: coalesced global -> regs -> transposed LDS scatter ----
    const __bf16* vsrc = vn + bh + (size_t)t*128*DD;
    bfx8 vr[4];
    #pragma unroll
    for (int i = 0; i < 4; ++i) {
      const int s = i*256 + tid;
      vr[i] = *(const bfx8*)(vsrc + (size_t)(s >> 3)*DD + (s & 7)*8);
    }
    #pragma unroll
    for (int i = 0; i < 4; ++i) {
      const int s = i*256 + tid;
      const int kv = s >> 3, d0 = (s & 7) * 8;
      #pragma unroll
      for (int j = 0; j < 8; ++j) {
        const int d = d0 + j;
        *(__bf16*)(Vt + d*256 + (((kv >> 3) ^ (d & 15)) * 16) + (kv & 7)*2) = vr[i][j];
      }
    }
    __syncthreads();   // K (vmcnt) + V (lgkm) staged for everyone

    // ---- S = Q K^T ----
    f32x4 S[2][8];
    #pragma unroll
    for (int nf = 0; nf < 8; ++nf) {
      const int r = nf*16 + l15;
      const bfx8 K0 = *(const bfx8*)(Ks + r*128 + (((0*4 + l4) ^ (r & 7)) * 16));
      const bfx8 K1 = *(const bfx8*)(Ks + r*128 + (((1*4 + l4) ^ (r & 7)) * 16));
      #pragma unroll
      for (int mf = 0; mf < 2; ++mf) {
        f32x4 sacc = zz;
        sacc = mfma16(Qf[mf][0], K0, sacc);
        sacc = mfma16(Qf[mf][1], K1, sacc);
        S[mf][nf] = sacc;
      }
    }

    // ---- + attn_bias (only if any nonzero; flag is data-deterministic) ----
    if (hasbias) {
      #pragma unroll
      for (int mf = 0; mf < 2; ++mf)
        #pragma unroll
        for (int rg = 0; rg < 4; ++rg) {
          const size_t qg = (size_t)(q0 + mf*16 + 4*l4 + rg);
          const float* bp = bias + qg*SEQ + (size_t)t*128;
          #pragma unroll
          for (int nf = 0; nf < 8; ++nf)
            S[mf][nf][rg] += bp[nf*16 + l15];
        }
    }

    // ---- online softmax (row = 16 lanes x 8 nf) ----
    #pragma unroll
    for (int mf = 0; mf < 2; ++mf)
      #pragma unroll
      for (int rg = 0; rg < 4; ++rg) {
        float mx = S[mf][0][rg];
        #pragma unroll
        for (int nf = 1; nf < 8; ++nf) mx = fmaxf(mx, S[mf][nf][rg]);
        mx = fmaxf(mx, __shfl_xor(mx, 1));
        mx = fmaxf(mx, __shfl_xor(mx, 2));
        mx = fmaxf(mx, __shfl_xor(mx, 4));
        mx = fmaxf(mx, __shfl_xor(mx, 8));
        const float mn = fmaxf(m_[mf][rg], mx);
        const float corr = __expf(m_[mf][rg] - mn);
        float rs = 0.f;
        #pragma unroll
        for (int nf = 0; nf < 8; ++nf) {
          const float pv = __expf(S[mf][nf][rg] - mn);
          S[mf][nf][rg] = pv;
          rs += pv;
        }
        rs += __shfl_xor(rs, 1); rs += __shfl_xor(rs, 2);
        rs += __shfl_xor(rs, 4); rs += __shfl_xor(rs, 8);
        l_[mf][rg] = l_[mf][rg] * corr + rs;
        m_[mf][rg] = mn;
        #pragma unroll
        for (int nd = 0; nd < 4; ++nd) O[mf][nd][rg] *= corr;
      }

    // ---- P -> per-wave LDS (transpose to A-operand layout) ----
    char* Pw = (char*)Ps[w];
    #pragma unroll
    for (int mf = 0; mf < 2; ++mf)
      #pragma unroll
      for (int nf = 0; nf < 8; ++nf)
        #pragma unroll
        for (int rg = 0; rg < 4; ++rg) {
          const int r = mf*16 + 4*l4 + rg;
          const int cc = nf*16 + l15;
          *(__bf16*)(Pw + r*256 + (((cc >> 3) ^ (r & 15)) * 16) + (cc & 7)*2) =
              (__bf16)S[mf][nf][rg];
        }

    // ---- O += P V ----
    #pragma unroll
    for (int kk = 0; kk < 4; ++kk) {
      bfx8 Pf[2];
      #pragma unroll
      for (int mf = 0; mf < 2; ++mf) {
        const int r = mf*16 + l15;
        Pf[mf] = *(const bfx8*)(Pw + r*256 + (((kk*4 + l4) ^ (r & 15)) * 16));
      }
      #pragma unroll
      for (int nd = 0; nd < 4; ++nd) {
        const int dr = nd*16 + l15;
        const bfx8 Vf = *(const bfx8*)(Vt + dr*256 + (((kk*4 + l4) ^ (dr & 15)) * 16));
        #pragma unroll
        for (int mf = 0; mf < 2; ++mf)
          O[mf][nd] = mfma16(Pf[mf], Vf, O[mf][nd]);
      }
    }
  }

  // ---- epilogue: O/l, write hi/lo bf16 split of attn output [B,L,C] ----
  #pragma unroll
  for (int mf = 0; mf < 2; ++mf)
    #pragma unroll
    for (int rg = 0; rg < 4; ++rg) {
      const float inv = 1.f / l_[mf][rg];
      const int qg = q0 + mf*16 + 4*l4 + rg;
      #pragma unroll
      for (int nd = 0; nd < 4; ++nd) {
        const float v = O[mf][nd][rg] * inv;
        const size_t idx = ((size_t)(b*SEQ + qg))*CH + h*DD + nd*16 + l15;
        const __bf16 hb = (__bf16)v;
        ao_hi[idx] = hb;
        ao_lo[idx] = (__bf16)(v - (float)hb);
      }
    }
}

// ---------------------------------------------------------------------------
extern "C" void kernel_launch(void* const* d_in, const int* in_sizes, int n_in,
                              void* d_out, int out_size, void* d_ws, size_t ws_size,
                              hipStream_t stream) {
  const float* x         = (const float*)d_in[0];  // [4,2048,1024]
  const float* attn_bias = (const float*)d_in[1];  // [1,1,2048,2048]
  const float* qkv_w     = (const float*)d_in[2];  // [3072,1024]
  const float* q_bias    = (const float*)d_in[3];  // [1024]
  const float* v_bias    = (const float*)d_in[4];  // [1024]
  const float* scale_mul = (const float*)d_in[5];  // [16]
  const float* proj_w    = (const float*)d_in[6];  // [1024,1024]
  const float* proj_b    = (const float*)d_in[7];  // [1024]
  float* out = (float*)d_out;

  char* ws = (char*)d_ws;
  size_t off = 0;
  auto alloc = [&](size_t n) { char* p = ws + off; off += (n + 255) & ~(size_t)255; return p; };
  __bf16* x_h  = (__bf16*)alloc((size_t)MROWS*CH*2);
  __bf16* x_l  = (__bf16*)alloc((size_t)MROWS*CH*2);
  __bf16* w_h  = (__bf16*)alloc((size_t)3*CH*CH*2);
  __bf16* w_l  = (__bf16*)alloc((size_t)3*CH*CH*2);
  __bf16* p_h  = (__bf16*)alloc((size_t)CH*CH*2);
  __bf16* p_l  = (__bf16*)alloc((size_t)CH*CH*2);
  __bf16* qkvn = (__bf16*)alloc((size_t)3*BHLD*2);
  __bf16* ao_h = (__bf16*)alloc((size_t)MROWS*CH*2);
  __bf16* ao_l = (__bf16*)alloc((size_t)MROWS*CH*2);
  int*    flag = (int*)alloc(256);

  split_kernel<<<MROWS*CH/4/256, 256, 0, stream>>>((const float4*)x, x_h, x_l, MROWS*CH/4);
  split_kernel<<<3*CH*CH/4/256, 256, 0, stream>>>((const float4*)qkv_w, w_h, w_l, 3*CH*CH/4);
  split_kernel<<<CH*CH/4/256, 256, 0, stream>>>((const float4*)proj_w, p_h, p_l, CH*CH/4);

  hipMemsetAsync(flag, 0, sizeof(int), stream);
  scan_nz<<<2048, 256, 0, stream>>>((const uint4*)attn_bias, SEQ*SEQ/4, flag);

  // GEMM1: [8192,3072] = x * qkv_w^T (+bias), scattered as bf16 qkvn[3][B,H,L,D]
  gemm128<1><<<(MROWS/128)*(3*CH/128), 256, 0, stream>>>(
      x_h, x_l, w_h, w_l, 3*CH/128, CH, q_bias, v_bias, nullptr, qkvn);

  // l2norm q,k (+ head scale on q), in place
  norml2<<<2*NB*NH*SEQ/32, 256, 0, stream>>>(qkvn, scale_mul);

  // flash attention
  attn_kernel<<<NB*NH*(SEQ/128), 256, 0, stream>>>(
      qkvn, qkvn + (size_t)BHLD, qkvn + 2*(size_t)BHLD, attn_bias, flag, ao_h, ao_l);

  // GEMM2: d_out = attn_out * proj_w^T + proj_b
  gemm128<2><<<(MROWS/128)*(CH/128), 256, 0, stream>>>(
      ao_h, ao_l, p_h, p_l, CH/128, CH, proj_b, nullptr, out, nullptr);
}

// Round 2
// 388.123 us; speedup vs baseline: 1.2694x; 1.2694x over previous
//
#include <hip/hip_runtime.h>
#include <cstdint>

// ---------------------------------------------------------------------------
// SelfAttention (QK-l2norm variant), MI355X/gfx950.
// R2: attention rebuilt — V pre-transposed in GEMM1 epilogue ([B,H,D,L]),
// swapped QK^T (S^T via mfma(K,Q), q lane-local) and swapped PV
// (O^T via mfma(Vt,P)). All LDS traffic is b64/b128, XOR-swizzled.
// Projections: Markidis hi/lo bf16 split (3 MFMAs) ~ fp32-accurate.
// ---------------------------------------------------------------------------

typedef __bf16 bfx8 __attribute__((ext_vector_type(8)));
typedef __bf16 bfx4 __attribute__((ext_vector_type(4)));
typedef float  f32x4 __attribute__((ext_vector_type(4)));

#define NB   4
#define NH   16
#define SEQ  2048
#define CH   1024
#define DD   64
#define MROWS (NB*SEQ)             /* 8192 */
#define BHLD  (NB*NH*SEQ*DD)       /* 8388608 */

__device__ __forceinline__ void async16(void* lds, const void* g) {
  __builtin_amdgcn_global_load_lds((const __attribute__((address_space(1))) void*)g,
                                   (__attribute__((address_space(3))) void*)lds, 16, 0, 0);
}
__device__ __forceinline__ f32x4 mfma16(bfx8 a, bfx8 b, f32x4 c) {
  return __builtin_amdgcn_mfma_f32_16x16x32_bf16(a, b, c, 0, 0, 0);
}

// --------------------------- hi/lo split (Markidis) -------------------------
__global__ __launch_bounds__(256) void split_kernel(const float4* __restrict__ src,
                                                    __bf16* __restrict__ hi,
                                                    __bf16* __restrict__ lo, int n4) {
  int i = blockIdx.x * 256 + threadIdx.x;
  if (i >= n4) return;
  float4 v = src[i];
  float vv[4] = {v.x, v.y, v.z, v.w};
  bfx4 h, l;
  #pragma unroll
  for (int j = 0; j < 4; ++j) {
    __bf16 hb = (__bf16)vv[j];
    h[j] = hb;
    l[j] = (__bf16)(vv[j] - (float)hb);
  }
  *(bfx4*)(hi + 4*(size_t)i) = h;
  *(bfx4*)(lo + 4*(size_t)i) = l;
}

// --------------------------- bias nonzero scan ------------------------------
__global__ __launch_bounds__(256) void scan_nz(const uint4* __restrict__ p, int n4,
                                               int* __restrict__ flag) {
  unsigned acc = 0;
  const int stride = gridDim.x * 256;
  for (int i = blockIdx.x * 256 + threadIdx.x; i < n4; i += stride) {
    uint4 u = p[i];
    acc |= (u.x | u.y | u.z | u.w) & 0x7fffffffu;
  }
  if (acc) atomicOr(flag, 1);
}

// --------------------------- split-bf16 GEMM (NT) ---------------------------
// C[M,N] = A[M,K] * B[N,K]^T, A/B hi/lo bf16 pairs. 128x128 tile, 4 waves,
// BK=32. EPI==1: +bias, q/k -> qkvn[2][B,H,L,D], v -> vt[B,H,D,L] (transposed).
// EPI==2: +proj_b, f32 d_out.
template<int EPI>
__global__ __launch_bounds__(256, 2) void gemm128(
    const __bf16* __restrict__ Agh, const __bf16* __restrict__ Agl,
    const __bf16* __restrict__ Bgh, const __bf16* __restrict__ Bgl,
    const int Ntiles, const int K,
    const float* __restrict__ biasA, const float* __restrict__ biasB,
    float* __restrict__ outF, __bf16* __restrict__ outQ, __bf16* __restrict__ outV)
{
  __shared__ alignas(16) char lds[32768];   // Ah | Al | Bh | Bl, 8KB each
  const int tid = threadIdx.x;
  const int lane = tid & 63, w = tid >> 6;
  const int l15 = lane & 15, l4 = lane >> 4;
  const int nwg = (int)gridDim.x;
  const int wk = (int)(blockIdx.x & 7) * (nwg >> 3) + (int)(blockIdx.x >> 3);
  const int mt = wk / Ntiles, nt = wk % Ntiles;
  const int m0 = mt * 128, n0 = nt * 128;
  const int wm = (w >> 1) * 64, wn = (w & 1) * 64;

  const f32x4 zz = {0.f, 0.f, 0.f, 0.f};
  f32x4 acc[4][4];
  #pragma unroll
  for (int a = 0; a < 4; ++a)
    #pragma unroll
    for (int b = 0; b < 4; ++b) acc[a][b] = zz;

  int st_row[2], st_c[2], st_lds[2];
  #pragma unroll
  for (int i = 0; i < 2; ++i) {
    const int s = i*256 + tid;
    st_row[i] = s >> 2;
    st_c[i]   = (s & 3) ^ ((st_row[i] >> 1) & 3);
    st_lds[i] = (i*256 + w*64) * 16;
  }

  for (int k0 = 0; k0 < K; k0 += 32) {
    __syncthreads();
    #pragma unroll
    for (int i = 0; i < 2; ++i) {
      const size_t ga = (size_t)(m0 + st_row[i]) * K + (size_t)(k0 + st_c[i]*8);
      const size_t gb = (size_t)(n0 + st_row[i]) * K + (size_t)(k0 + st_c[i]*8);
      async16(lds +         st_lds[i], Agh + ga);
      async16(lds +  8192 + st_lds[i], Agl + ga);
      async16(lds + 16384 + st_lds[i], Bgh + gb);
      async16(lds + 24576 + st_lds[i], Bgl + gb);
    }
    __syncthreads();

    bfx8 ah[4], al[4], bh[4], bl[4];
    #pragma unroll
    for (int f = 0; f < 4; ++f) {
      const int ra = wm + f*16 + l15;
      const int oa = ra*64 + ((l4 ^ ((ra >> 1) & 3)) * 16);
      ah[f] = *(const bfx8*)(lds + oa);
      al[f] = *(const bfx8*)(lds + 8192 + oa);
      const int rb = wn + f*16 + l15;
      const int ob = rb*64 + ((l4 ^ ((rb >> 1) & 3)) * 16);
      bh[f] = *(const bfx8*)(lds + 16384 + ob);
      bl[f] = *(const bfx8*)(lds + 24576 + ob);
    }
    __builtin_amdgcn_s_setprio(1);
    #pragma unroll
    for (int mf = 0; mf < 4; ++mf)
      #pragma unroll
      for (int nf = 0; nf < 4; ++nf) {
        acc[mf][nf] = mfma16(al[mf], bh[nf], acc[mf][nf]);
        acc[mf][nf] = mfma16(ah[mf], bl[nf], acc[mf][nf]);
        acc[mf][nf] = mfma16(ah[mf], bh[nf], acc[mf][nf]);
      }
    __builtin_amdgcn_s_setprio(0);
  }

  // epilogue: C/D layout col=lane&15, row=4*(lane>>4)+reg
  #pragma unroll
  for (int mf = 0; mf < 4; ++mf)
    #pragma unroll
    for (int nf = 0; nf < 4; ++nf)
      #pragma unroll
      for (int rg = 0; rg < 4; ++rg) {
        const int gr = m0 + wm + mf*16 + 4*l4 + rg;
        const int gc = n0 + wn + nf*16 + l15;
        float v = acc[mf][nf][rg];
        if (EPI == 1) {
          v += (gc < CH) ? biasA[gc] : ((gc >= 2*CH) ? biasB[gc - 2*CH] : 0.f);
          const int which = gc >> 10, cc = gc & (CH-1);
          const int hh = cc >> 6, dd = cc & 63;
          const int bb = gr >> 11, ll = gr & (SEQ-1);
          if (which < 2)
            outQ[(size_t)which*BHLD + ((size_t)((bb*NH + hh)*SEQ) + ll)*DD + dd] = (__bf16)v;
          else
            outV[((size_t)(bb*NH + hh)*DD + dd)*SEQ + ll] = (__bf16)v;
        } else {
          outF[(size_t)gr*CH + gc] = v + biasA[gc];
        }
      }
}

// --------------------------- l2 normalize q,k (in place) --------------------
__global__ __launch_bounds__(256) void norml2(__bf16* __restrict__ qk,
                                              const float* __restrict__ scale_mul) {
  const int tid = threadIdx.x;
  const int rid = blockIdx.x * 32 + (tid >> 3);
  const int e0 = (tid & 7) * 8;
  const int r = rid & (131072 - 1);
  const bool isq = rid < 131072;
  const int hh = (r >> 11) & 15;
  float sm = 1.f;
  if (isq) sm = __expf(fminf(scale_mul[hh], 4.605170185988091f));
  __bf16* p = qk + (size_t)rid * DD + e0;
  bfx8 v = *(bfx8*)p;
  float f[8]; float ss = 0.f;
  #pragma unroll
  for (int j = 0; j < 8; ++j) { f[j] = (float)v[j]; ss += f[j]*f[j]; }
  ss += __shfl_xor(ss, 1); ss += __shfl_xor(ss, 2); ss += __shfl_xor(ss, 4);
  const float sc = sm / fmaxf(sqrtf(ss), 1e-12f);
  #pragma unroll
  for (int j = 0; j < 8; ++j) v[j] = (__bf16)(f[j] * sc);
  *(bfx8*)p = v;
}

// --------------------------- flash attention (bf16, swapped ops) ------------
// Block = (b,h,qtile 128). 4 waves x 32 q. KV tiles 128.
// Ks[128k][64d]  global_load_lds, chunk ^= row&7   (8x16B rows)
// Vt[64d][128k]  global_load_lds from vt[B,H,D,L], chunk ^= row&15 (16x16B rows)
// S^T = mfma(K,Q): lane holds q=l15, k=16nf+4*l4+rg -> softmax lane-local+2shfl
// P: bfx4 pack (4 consecutive k) -> Ps[q][k] b64 swizzled writes
// O^T = mfma(Vt,P): lane holds q=l15, d=16nd+4*l4+rg -> bfx4 global stores
__global__ __launch_bounds__(256, 2) void attn_kernel(
    const __bf16* __restrict__ qn, const __bf16* __restrict__ kn,
    const __bf16* __restrict__ vtg,
    const float* __restrict__ bias, const int* __restrict__ flag,
    __bf16* __restrict__ ao_hi, __bf16* __restrict__ ao_lo)
{
  __shared__ alignas(16) char Ks[16384];
  __shared__ alignas(16) char Vt[16384];
  __shared__ alignas(16) char Ps[32768];

  const int tid = threadIdx.x, lane = tid & 63, w = tid >> 6;
  const int l15 = lane & 15, l4 = lane >> 4;
  const int wk = (int)(blockIdx.x & 7) * 128 + (int)(blockIdx.x >> 3);
  const int qt = wk & 15, h = (wk >> 4) & 15, b = wk >> 8;
  const size_t bh = ((size_t)(b*NH + h)) * SEQ * DD;
  const int hasbias = *flag;
  char* Pw = Ps + w*8192;

  // Q fragments (B-operand: col=lane&15=q, k=8*(lane>>4)+j)
  bfx8 Qf[2][2];
  const int q0 = qt*128 + w*32;
  #pragma unroll
  for (int mf = 0; mf < 2; ++mf)
    #pragma unroll
    for (int kd = 0; kd < 2; ++kd)
      Qf[mf][kd] = *(const bfx8*)(qn + bh + (size_t)(q0 + mf*16 + l15)*DD + kd*32 + l4*8);

  const f32x4 zz = {0.f, 0.f, 0.f, 0.f};
  f32x4 O[2][4];
  float m_[2] = {-1e30f, -1e30f}, l_[2] = {0.f, 0.f};
  #pragma unroll
  for (int mf = 0; mf < 2; ++mf)
    #pragma unroll
    for (int nd = 0; nd < 4; ++nd) O[mf][nd] = zz;

  for (int t = 0; t < 16; ++t) {
    __syncthreads();   // all waves done reading Ks/Vt of previous tile

    // ---- stage K [128][64] (async, pre-swizzled source) ----
    const __bf16* ksrc = kn + bh + (size_t)t*128*DD;
    #pragma unroll
    for (int i = 0; i < 4; ++i) {
      const int s = i*256 + tid;
      const int row = s >> 3;
      const int c = (s & 7) ^ (row & 7);
      async16(Ks + (size_t)(i*256 + w*64)*16, ksrc + (size_t)row*DD + c*8);
    }
    // ---- stage V^T [64][128] (async, pre-swizzled source) ----
    const __bf16* vsrc = vtg + bh + (size_t)t*128;
    #pragma unroll
    for (int i = 0; i < 4; ++i) {
      const int s = i*256 + tid;
      const int row = s >> 4;                     // d
      const int c = (s & 15) ^ (row & 15);
      async16(Vt + (size_t)(i*256 + w*64)*16, vsrc + (size_t)row*SEQ + c*8);
    }
    __syncthreads();   // vmcnt drained by compiler before barrier

    // ---- S^T = K Q^T : lane holds q=l15(+16mf), k=16nf+4*l4+rg ----
    f32x4 ST[2][8];
    __builtin_amdgcn_s_setprio(1);
    #pragma unroll
    for (int nf = 0; nf < 8; ++nf) {
      const int r = nf*16 + l15;
      const bfx8 K0 = *(const bfx8*)(Ks + r*128 + ((l4 ^ (r & 7)) * 16));
      const bfx8 K1 = *(const bfx8*)(Ks + r*128 + (((4 + l4) ^ (r & 7)) * 16));
      #pragma unroll
      for (int mf = 0; mf < 2; ++mf) {
        f32x4 sacc = mfma16(K0, Qf[mf][0], zz);
        ST[mf][nf] = mfma16(K1, Qf[mf][1], sacc);
      }
    }
    __builtin_amdgcn_s_setprio(0);

    if (hasbias) {
      #pragma unroll
      for (int mf = 0; mf < 2; ++mf) {
        const size_t qg = (size_t)(q0 + mf*16 + l15);
        const float* bp = bias + qg*SEQ + (size_t)t*128;
        #pragma unroll
        for (int nf = 0; nf < 8; ++nf)
          #pragma unroll
          for (int rg = 0; rg < 4; ++rg)
            ST[mf][nf][rg] += bp[nf*16 + 4*l4 + rg];
      }
    }

    // ---- online softmax (q fully lane-local; reduce over nf,rg + l4 via shfl)
    #pragma unroll
    for (int mf = 0; mf < 2; ++mf) {
      f32x4 mv = ST[mf][0];
      #pragma unroll
      for (int nf = 1; nf < 8; ++nf)
        #pragma unroll
        for (int rg = 0; rg < 4; ++rg) mv[rg] = fmaxf(mv[rg], ST[mf][nf][rg]);
      float mx = fmaxf(fmaxf(mv[0], mv[1]), fmaxf(mv[2], mv[3]));
      mx = fmaxf(mx, __shfl_xor(mx, 16));
      mx = fmaxf(mx, __shfl_xor(mx, 32));
      const float mn = fmaxf(m_[mf], mx);
      const float corr = __expf(m_[mf] - mn);
      f32x4 sv = zz;
      #pragma unroll
      for (int nf = 0; nf < 8; ++nf) {
        #pragma unroll
        for (int rg = 0; rg < 4; ++rg) {
          ST[mf][nf][rg] = __expf(ST[mf][nf][rg] - mn);
          sv[rg] += ST[mf][nf][rg];
        }
      }
      float rs = (sv[0] + sv[1]) + (sv[2] + sv[3]);
      rs += __shfl_xor(rs, 16);
      rs += __shfl_xor(rs, 32);
      l_[mf] = l_[mf] * corr + rs;
      m_[mf] = mn;
      #pragma unroll
      for (int nd = 0; nd < 4; ++nd)
        #pragma unroll
        for (int rg = 0; rg < 4; ++rg) O[mf][nd][rg] *= corr;

      // ---- P -> Ps[q=32][k=128] per wave, b64 swizzled writes ----
      const int row = mf*16 + l15;
      #pragma unroll
      for (int nf = 0; nf < 8; ++nf) {
        bfx4 p4;
        #pragma unroll
        for (int rg = 0; rg < 4; ++rg) p4[rg] = (__bf16)ST[mf][nf][rg];
        const int cpos = (2*nf + (l4 >> 1)) ^ l15;   // row&15 == l15
        *(bfx4*)(Pw + row*256 + cpos*16 + (l4 & 1)*8) = p4;
      }
    }

    // ---- O^T += V^T P : lane holds q=l15(+16mf), d=16nd+4*l4+rg ----
    __builtin_amdgcn_s_setprio(1);
    #pragma unroll
    for (int kk = 0; kk < 4; ++kk) {
      bfx8 Pf[2];
      #pragma unroll
      for (int mf = 0; mf < 2; ++mf)
        Pf[mf] = *(const bfx8*)(Pw + (mf*16 + l15)*256 + (((4*kk + l4) ^ l15) * 16));
      #pragma unroll
      for (int nd = 0; nd < 4; ++nd) {
        const bfx8 Vf = *(const bfx8*)(Vt + (nd*16 + l15)*256 + (((4*kk + l4) ^ l15) * 16));
        #pragma unroll
        for (int mf = 0; mf < 2; ++mf)
          O[mf][nd] = mfma16(Vf, Pf[mf], O[mf][nd]);
      }
    }
    __builtin_amdgcn_s_setprio(0);
  }

  // ---- epilogue: O/l, hi/lo bf16 split, bfx4 stores (d consecutive) ----
  #pragma unroll
  for (int mf = 0; mf < 2; ++mf) {
    const float inv = 1.f / l_[mf];
    const int qg = q0 + mf*16 + l15;
    #pragma unroll
    for (int nd = 0; nd < 4; ++nd) {
      bfx4 hb, lb;
      #pragma unroll
      for (int rg = 0; rg < 4; ++rg) {
        const float v = O[mf][nd][rg] * inv;
        hb[rg] = (__bf16)v;
        lb[rg] = (__bf16)(v - (float)hb[rg]);
      }
      const size_t idx = ((size_t)(b*SEQ + qg))*CH + h*DD + nd*16 + 4*l4;
      *(bfx4*)(ao_hi + idx) = hb;
      *(bfx4*)(ao_lo + idx) = lb;
    }
  }
}

// ---------------------------------------------------------------------------
extern "C" void kernel_launch(void* const* d_in, const int* in_sizes, int n_in,
                              void* d_out, int out_size, void* d_ws, size_t ws_size,
                              hipStream_t stream) {
  const float* x         = (const float*)d_in[0];
  const float* attn_bias = (const float*)d_in[1];
  const float* qkv_w     = (const float*)d_in[2];
  const float* q_bias    = (const float*)d_in[3];
  const float* v_bias    = (const float*)d_in[4];
  const float* scale_mul = (const float*)d_in[5];
  const float* proj_w    = (const float*)d_in[6];
  const float* proj_b    = (const float*)d_in[7];
  float* out = (float*)d_out;

  char* ws = (char*)d_ws;
  size_t off = 0;
  auto alloc = [&](size_t n) { char* p = ws + off; off += (n + 255) & ~(size_t)255; return p; };
  __bf16* x_h  = (__bf16*)alloc((size_t)MROWS*CH*2);
  __bf16* x_l  = (__bf16*)alloc((size_t)MROWS*CH*2);
  __bf16* w_h  = (__bf16*)alloc((size_t)3*CH*CH*2);
  __bf16* w_l  = (__bf16*)alloc((size_t)3*CH*CH*2);
  __bf16* p_h  = (__bf16*)alloc((size_t)CH*CH*2);
  __bf16* p_l  = (__bf16*)alloc((size_t)CH*CH*2);
  __bf16* qkvn = (__bf16*)alloc((size_t)2*BHLD*2);   // q,k [B,H,L,D]
  __bf16* vt   = (__bf16*)alloc((size_t)BHLD*2);     // v   [B,H,D,L]
  __bf16* ao_h = (__bf16*)alloc((size_t)MROWS*CH*2);
  __bf16* ao_l = (__bf16*)alloc((size_t)MROWS*CH*2);
  int*    flag = (int*)alloc(256);

  split_kernel<<<MROWS*CH/4/256, 256, 0, stream>>>((const float4*)x, x_h, x_l, MROWS*CH/4);
  split_kernel<<<3*CH*CH/4/256, 256, 0, stream>>>((const float4*)qkv_w, w_h, w_l, 3*CH*CH/4);
  split_kernel<<<CH*CH/4/256, 256, 0, stream>>>((const float4*)proj_w, p_h, p_l, CH*CH/4);

  hipMemsetAsync(flag, 0, sizeof(int), stream);
  scan_nz<<<2048, 256, 0, stream>>>((const uint4*)attn_bias, SEQ*SEQ/4, flag);

  gemm128<1><<<(MROWS/128)*(3*CH/128), 256, 0, stream>>>(
      x_h, x_l, w_h, w_l, 3*CH/128, CH, q_bias, v_bias, nullptr, qkvn, vt);

  norml2<<<2*NB*NH*SEQ/32, 256, 0, stream>>>(qkvn, scale_mul);

  attn_kernel<<<NB*NH*(SEQ/128), 256, 0, stream>>>(
      qkvn, qkvn + (size_t)BHLD, vt, attn_bias, flag, ao_h, ao_l);

  gemm128<2><<<(MROWS/128)*(CH/128), 256, 0, stream>>>(
      ao_h, ao_l, p_h, p_l, CH/128, CH, proj_b, nullptr, out, nullptr, nullptr);
}